// Round 9
// baseline (166.856 us; speedup 1.0000x reference)
//
#include <hip/hip_runtime.h>
#include <hip/hip_bf16.h>
#include <math.h>

// Problem constants
#define BB 4
#define TT 2048
#define CC 1024
#define HH 16
#define HD 64
#define C3 3072
#define MM (BB * TT)   // 8192

typedef __attribute__((ext_vector_type(8))) short bf16x8;  // MFMA A/B frag (4 VGPRs)
typedef __attribute__((ext_vector_type(4))) float f32x4;   // MFMA C/D frag
typedef __attribute__((ext_vector_type(4))) short s16x4;

__device__ inline short f32_to_bf16_bits(float f) {
    unsigned u = __float_as_uint(f);
    u += 0x7fffu + ((u >> 16) & 1u);   // round-to-nearest-even
    return (short)(u >> 16);
}

__device__ inline void async_copy16(const void* g, void* l) {
    __builtin_amdgcn_global_load_lds((const __attribute__((address_space(1))) void*)g,
                                     (__attribute__((address_space(3))) void*)l, 16, 0, 0);
}

// ---------------- cast x: fp32 -> bf16, flat, 8 elems/thread
__global__ __launch_bounds__(256) void cast_x(const float* __restrict__ in,
                                              short* __restrict__ out) {
    int i = (blockIdx.x * 256 + threadIdx.x) * 8;
    float4 a = *(const float4*)(in + i);
    float4 b = *(const float4*)(in + i + 4);
    bf16x8 o;
    o[0] = f32_to_bf16_bits(a.x); o[1] = f32_to_bf16_bits(a.y);
    o[2] = f32_to_bf16_bits(a.z); o[3] = f32_to_bf16_bits(a.w);
    o[4] = f32_to_bf16_bits(b.x); o[5] = f32_to_bf16_bits(b.y);
    o[6] = f32_to_bf16_bits(b.z); o[7] = f32_to_bf16_bits(b.w);
    *(bf16x8*)(out + i) = o;
}

// ---------------- transpose-cast: w[K][N] fp32 -> wt[N][K] bf16, 64x64 tiles
__global__ __launch_bounds__(256) void tcast(const float* __restrict__ w,
                                             short* __restrict__ wt,
                                             int K, int N) {
    __shared__ short tile[64][68];
    const int n0 = blockIdx.x * 64, k0 = blockIdx.y * 64;
    const int tid = threadIdx.x;
#pragma unroll
    for (int it = 0; it < 4; ++it) {
        int idx = it * 1024 + tid * 4;
        int r = idx >> 6, c = idx & 63;
        float4 v = *(const float4*)&w[(size_t)(k0 + r) * N + n0 + c];
        tile[r][c + 0] = f32_to_bf16_bits(v.x);
        tile[r][c + 1] = f32_to_bf16_bits(v.y);
        tile[r][c + 2] = f32_to_bf16_bits(v.z);
        tile[r][c + 3] = f32_to_bf16_bits(v.w);
    }
    __syncthreads();
#pragma unroll
    for (int it = 0; it < 4; ++it) {
        int idx = it * 256 + tid;
        int rr = idx >> 4, kc = (idx & 15) * 4;
        s16x4 o = { tile[kc + 0][rr], tile[kc + 1][rr], tile[kc + 2][rr], tile[kc + 3][rr] };
        *(s16x4*)&wt[(size_t)(n0 + rr) * K + k0 + kc] = o;
    }
}

// ---------------- bf16 MFMA GEMM v2.2 (r8): 128x128 tile, BK=64, xor-swizzled LDS,
// n-column-grouped XCD swizzle (neutral but kept with r8 best total).
template <bool QKV>
__global__ __launch_bounds__(256) void gemm128(const short* __restrict__ A,
                                               const short* __restrict__ Bt,
                                               const float* __restrict__ bias,
                                               short* __restrict__ qb,
                                               short* __restrict__ kb,
                                               short* __restrict__ vt,
                                               float* __restrict__ out,
                                               int N, int Kdim) {
    __shared__ __align__(16) short As[128 * 64];
    __shared__ __align__(16) short Bs[128 * 64];
    const int tid = threadIdx.x;
    const int wave = tid >> 6, lane = tid & 63;
    const int quad = lane >> 4, l16 = lane & 15;
    const int wm = wave >> 1, wn = wave & 1;

    const int nbx = gridDim.x;
    const int cpc = nbx >> 3;                       // columns per class
    const int id = blockIdx.y * nbx + blockIdx.x;
    const int cls = id & 7;
    const int rr = id >> 3;
    const int n_idx = cls * cpc + rr % cpc;
    const int m_idx = rr / cpc;
    const int m0 = m_idx * 128, n0 = n_idx * 128;

    f32x4 acc[4][4] = {};

    for (int k0 = 0; k0 < Kdim; k0 += 64) {
#pragma unroll
        for (int c2 = 0; c2 < 4; ++c2) {
            int g = (wave * 4 + c2) * 64 + lane;      // 0..1023 staging unit
            int row = g >> 3;
            int seg = (g & 7) ^ (row & 7);            // xor swizzle
            async_copy16(A + (size_t)(m0 + row) * Kdim + k0 + seg * 8, As + g * 8);
            async_copy16(Bt + (size_t)(n0 + row) * Kdim + k0 + seg * 8, Bs + g * 8);
        }
        __syncthreads();
#pragma unroll
        for (int ks = 0; ks < 2; ++ks) {
            bf16x8 af[4], bfv[4];
#pragma unroll
            for (int i = 0; i < 4; ++i) {
                int row = wm * 64 + i * 16 + l16;
                int u = (ks * 4 + quad) ^ (row & 7);
                af[i] = *(const bf16x8*)&As[row * 64 + u * 8];
            }
#pragma unroll
            for (int j = 0; j < 4; ++j) {
                int row = wn * 64 + j * 16 + l16;
                int u = (ks * 4 + quad) ^ (row & 7);
                bfv[j] = *(const bf16x8*)&Bs[row * 64 + u * 8];
            }
#pragma unroll
            for (int i = 0; i < 4; ++i)
#pragma unroll
                for (int j = 0; j < 4; ++j)
                    acc[i][j] = __builtin_amdgcn_mfma_f32_16x16x32_bf16(af[i], bfv[j], acc[i][j], 0, 0, 0);
        }
        __syncthreads();
    }

#pragma unroll
    for (int i = 0; i < 4; ++i)
#pragma unroll
        for (int j = 0; j < 4; ++j) {
            int n = n0 + wn * 64 + j * 16 + l16;
            float bv = bias[n];
            if (QKV) {
                int which = n >> 10, cc = n & 1023;
                int h = cc >> 6, d = cc & 63;
                if (which == 2) {
                    // v^T: lane's 4 r-values are 4 consecutive t at fixed d -> one 8B store
                    int m_base = m0 + wm * 64 + i * 16 + quad * 4;
                    int bb = m_base >> 11, t0 = m_base & 2047;
                    unsigned p0 = ((unsigned)(unsigned short)f32_to_bf16_bits(acc[i][j][0] + bv)) |
                                  ((unsigned)(unsigned short)f32_to_bf16_bits(acc[i][j][1] + bv) << 16);
                    unsigned p1 = ((unsigned)(unsigned short)f32_to_bf16_bits(acc[i][j][2] + bv)) |
                                  ((unsigned)(unsigned short)f32_to_bf16_bits(acc[i][j][3] + bv) << 16);
                    uint2 pk = {p0, p1};
                    *(uint2*)(vt + (((size_t)bb * HH + h) * HD + d) * TT + t0) = pk;
                } else {
                    // q-scale folds 1/sqrt(hd)=0.125 AND log2(e) so flash uses raw v_exp_f32 (exp2)
#pragma unroll
                    for (int r = 0; r < 4; ++r) {
                        int m = m0 + wm * 64 + i * 16 + quad * 4 + r;
                        int bb = m >> 11, t = m & 2047;
                        short val = f32_to_bf16_bits((acc[i][j][r] + bv) *
                                                     (which == 0 ? 0.18033688011112042f : 1.0f));
                        size_t off = (((size_t)bb * HH + h) * TT + t) * HD + d;
                        if (which == 0) qb[off] = val;
                        else kb[off] = val;
                    }
                }
            } else {
#pragma unroll
                for (int r = 0; r < 4; ++r) {
                    int m = m0 + wm * 64 + i * 16 + quad * 4 + r;
                    out[(size_t)m * N + n] = acc[i][j][r] + bv;
                }
            }
        }
}

// ---------------- Flash attention v7: 3-deep K/V ring, ONE barrier per iteration,
// prefetch flight = 2 iterations. Hazard chain (verified):
//  - top-of-iter vmcnt(2) completes pair t (outstanding at top = pairs {t,t+1});
//  - the barrier then certifies ALL waves' pair-t loads landed before any read;
//  - prefetch of pair t+2 (buf (t+2)%3) is issued AFTER the barrier, and that
//    buffer's previous readers (iter t-1) all passed this barrier;
//  - the next writer of buf t%3 issues only after barrier(t+1), which readers of
//    iter t reach only after finishing their reads.
// plds is bf16 (direct bf16x8 read for PV A-frag; store via cvt_pk(p,p) — same RNE
// as the old read-side cvt_pk, bit-identical output). LDS total 67.5KB (unchanged,
// 2 blocks/CU). XCD-locality bh-grouping swizzle kept (r7 win).
__global__ __launch_bounds__(512, 4) void flash_attn(const short* __restrict__ qb,
                                                     const short* __restrict__ kb,
                                                     const short* __restrict__ vt,
                                                     short* __restrict__ ab) {
    __shared__ __align__(16) short Ksh[3][4096];
    __shared__ __align__(16) short Vsh[3][4096];
    __shared__ __align__(16) short plds[8][16][72];   // P as bf16

    const int tid = threadIdx.x;
    const int wave = tid >> 6;
    const int lane = tid & 63;
    const int quad = lane >> 4;
    const int l16 = lane & 15;

    // XCD-locality swizzle: bijection [0,512) -> (bh, i) with bh-group constant per n&7
    const int n_hw = blockIdx.y * 8 + blockIdx.x;
    const int lgc = (n_hw & 7) * 64 + (n_hw >> 3);
    const int bh = lgc >> 3;
    const int i = lgc & 7;

    const int njt = 32 - 2 * i;                       // >= 18
    const int q_lo = i * 128 + wave * 16;
    const int q_hi = (15 - i) * 128 + wave * 16;

    const short* qball = qb + (size_t)bh * TT * HD;
    const short* kball = kb + (size_t)bh * TT * HD;
    const short* vtall = vt + (size_t)bh * HD * TT;

    const int sidx = wave * 64 + lane;
    const int srow = sidx >> 3;
    const int sseg = (sidx & 7) ^ (srow & 7);
    const short* kgsrc = kball + (size_t)srow * HD + sseg * 8;
    const short* vgsrc = vtall + (size_t)srow * TT + sseg * 8;

    bf16x8 qfh[2], qfl[2];
#pragma unroll
    for (int h = 0; h < 2; ++h) {
        qfh[h] = *(const bf16x8*)(qball + (size_t)(q_hi + l16) * HD + h * 32 + quad * 8);
        qfl[h] = *(const bf16x8*)(qball + (size_t)(q_lo + l16) * HD + h * 32 + quad * 8);
    }

    f32x4 o_hi[4] = {}, o_lo[4] = {};
    float ls_hi[4] = {0.f, 0.f, 0.f, 0.f}, ls_lo[4] = {0.f, 0.f, 0.f, 0.f};

    // prologue: stage tiles 0 and 1 (pairs issued in order: K0,V0,K1,V1)
    async_copy16(kgsrc, &Ksh[0][wave * 512]);
    async_copy16(vgsrc, &Vsh[0][wave * 512]);
    async_copy16(kgsrc + (size_t)64 * HD, &Ksh[1][wave * 512]);
    async_copy16(vgsrc + 64, &Vsh[1][wave * 512]);

    int buf = 0;
    for (int jt = 0; jt < njt; ++jt) {
        if (jt == njt - 1) { asm volatile("s_waitcnt vmcnt(0)" : : : "memory"); }
        else               { asm volatile("s_waitcnt vmcnt(2)" : : : "memory"); }
        __builtin_amdgcn_sched_barrier(0);
        __builtin_amdgcn_s_barrier();
        __builtin_amdgcn_sched_barrier(0);
        if (jt + 2 < njt) {
            int pbuf = (buf >= 1) ? buf - 1 : 2;      // (jt+2)%3
            async_copy16(kgsrc + (size_t)(jt + 2) * 64 * HD, &Ksh[pbuf][wave * 512]);
            async_copy16(vgsrc + (jt + 2) * 64, &Vsh[pbuf][wave * 512]);
        }

        const int j0 = jt * 64;

        if (j0 <= q_hi + 15) {
            f32x4 s[4];
            __builtin_amdgcn_s_setprio(1);
#pragma unroll
            for (int cb = 0; cb < 4; ++cb) {
                int row = cb * 16 + l16;
                bf16x8 k0 = *(const bf16x8*)&Ksh[buf][(row * 8 + (quad ^ (row & 7))) * 8];
                bf16x8 k1 = *(const bf16x8*)&Ksh[buf][(row * 8 + ((4 + quad) ^ (row & 7))) * 8];
                f32x4 a = {};
                a = __builtin_amdgcn_mfma_f32_16x16x32_bf16(qfh[0], k0, a, 0, 0, 0);
                a = __builtin_amdgcn_mfma_f32_16x16x32_bf16(qfh[1], k1, a, 0, 0, 0);
                s[cb] = a;
            }
            __builtin_amdgcn_s_setprio(0);
            if (j0 + 64 > q_hi) {
#pragma unroll
                for (int cb = 0; cb < 4; ++cb) {
                    int j = j0 + cb * 16 + l16;
#pragma unroll
                    for (int r = 0; r < 4; ++r)
                        if (j > q_hi + quad * 4 + r) s[cb][r] = -1e30f;
                }
            }
#pragma unroll
            for (int cb = 0; cb < 4; ++cb)
#pragma unroll
                for (int r = 0; r < 4; ++r) {
                    float p;
                    asm("v_exp_f32 %0, %1" : "=v"(p) : "v"(s[cb][r]));
                    ls_hi[r] += p;
                    unsigned pk;
                    asm("v_cvt_pk_bf16_f32 %0, %1, %2" : "=v"(pk) : "v"(p), "v"(p));
                    plds[wave][quad * 4 + r][cb * 16 + l16] = (short)pk;
                }
            {
                bf16x8 pa0 = *(const bf16x8*)&plds[wave][l16][quad * 8];
                bf16x8 pa1 = *(const bf16x8*)&plds[wave][l16][32 + quad * 8];
                __builtin_amdgcn_s_setprio(1);
#pragma unroll
                for (int db = 0; db < 4; ++db) {
                    int row = db * 16 + l16;
                    bf16x8 v0 = *(const bf16x8*)&Vsh[buf][(row * 8 + (quad ^ (row & 7))) * 8];
                    bf16x8 v1 = *(const bf16x8*)&Vsh[buf][(row * 8 + ((4 + quad) ^ (row & 7))) * 8];
                    o_hi[db] = __builtin_amdgcn_mfma_f32_16x16x32_bf16(pa0, v0, o_hi[db], 0, 0, 0);
                    o_hi[db] = __builtin_amdgcn_mfma_f32_16x16x32_bf16(pa1, v1, o_hi[db], 0, 0, 0);
                }
                __builtin_amdgcn_s_setprio(0);
            }
        }

        if (j0 <= q_lo + 15) {
            f32x4 s[4];
            __builtin_amdgcn_s_setprio(1);
#pragma unroll
            for (int cb = 0; cb < 4; ++cb) {
                int row = cb * 16 + l16;
                bf16x8 k0 = *(const bf16x8*)&Ksh[buf][(row * 8 + (quad ^ (row & 7))) * 8];
                bf16x8 k1 = *(const bf16x8*)&Ksh[buf][(row * 8 + ((4 + quad) ^ (row & 7))) * 8];
                f32x4 a = {};
                a = __builtin_amdgcn_mfma_f32_16x16x32_bf16(qfl[0], k0, a, 0, 0, 0);
                a = __builtin_amdgcn_mfma_f32_16x16x32_bf16(qfl[1], k1, a, 0, 0, 0);
                s[cb] = a;
            }
            __builtin_amdgcn_s_setprio(0);
            if (j0 + 64 > q_lo) {
#pragma unroll
                for (int cb = 0; cb < 4; ++cb) {
                    int j = j0 + cb * 16 + l16;
#pragma unroll
                    for (int r = 0; r < 4; ++r)
                        if (j > q_lo + quad * 4 + r) s[cb][r] = -1e30f;
                }
            }
#pragma unroll
            for (int cb = 0; cb < 4; ++cb)
#pragma unroll
                for (int r = 0; r < 4; ++r) {
                    float p;
                    asm("v_exp_f32 %0, %1" : "=v"(p) : "v"(s[cb][r]));
                    ls_lo[r] += p;
                    unsigned pk;
                    asm("v_cvt_pk_bf16_f32 %0, %1, %2" : "=v"(pk) : "v"(p), "v"(p));
                    plds[wave][quad * 4 + r][cb * 16 + l16] = (short)pk;
                }
            {
                bf16x8 pa0 = *(const bf16x8*)&plds[wave][l16][quad * 8];
                bf16x8 pa1 = *(const bf16x8*)&plds[wave][l16][32 + quad * 8];
                __builtin_amdgcn_s_setprio(1);
#pragma unroll
                for (int db = 0; db < 4; ++db) {
                    int row = db * 16 + l16;
                    bf16x8 v0 = *(const bf16x8*)&Vsh[buf][(row * 8 + (quad ^ (row & 7))) * 8];
                    bf16x8 v1 = *(const bf16x8*)&Vsh[buf][(row * 8 + ((4 + quad) ^ (row & 7))) * 8];
                    o_lo[db] = __builtin_amdgcn_mfma_f32_16x16x32_bf16(pa0, v0, o_lo[db], 0, 0, 0);
                    o_lo[db] = __builtin_amdgcn_mfma_f32_16x16x32_bf16(pa1, v1, o_lo[db], 0, 0, 0);
                }
                __builtin_amdgcn_s_setprio(0);
            }
        }
        buf = (buf == 2) ? 0 : buf + 1;
    }

    const int b = bh >> 4, hd0 = (bh & 15) * HD;
    float inv_h[4], inv_l[4];
#pragma unroll
    for (int r = 0; r < 4; ++r) {
        float th = ls_hi[r], tl = ls_lo[r];
#pragma unroll
        for (int off = 1; off < 16; off <<= 1) {
            th += __shfl_xor(th, off, 64);
            tl += __shfl_xor(tl, off, 64);
        }
        inv_h[r] = 1.0f / th;
        inv_l[r] = 1.0f / tl;
    }
#pragma unroll
    for (int r = 0; r < 4; ++r) {
        int qh = q_hi + quad * 4 + r;
        int ql = q_lo + quad * 4 + r;
#pragma unroll
        for (int db = 0; db < 4; ++db) {
            ab[((size_t)(b * TT + qh)) * CC + hd0 + db * 16 + l16] =
                f32_to_bf16_bits(o_hi[db][r] * inv_h[r]);
            ab[((size_t)(b * TT + ql)) * CC + hd0 + db * 16 + l16] =
                f32_to_bf16_bits(o_lo[db][r] * inv_l[r]);
        }
    }
}

extern "C" void kernel_launch(void* const* d_in, const int* in_sizes, int n_in,
                              void* d_out, int out_size, void* d_ws, size_t ws_size,
                              hipStream_t stream) {
    const float* x      = (const float*)d_in[0];
    const float* w_attn = (const float*)d_in[1];
    const float* b_attn = (const float*)d_in[2];
    const float* w_proj = (const float*)d_in[3];
    const float* b_proj = (const float*)d_in[4];
    float* out = (float*)d_out;

    const size_t per = (size_t)BB * HH * TT * HD;  // 8,388,608
    short* xb      = (short*)d_ws;
    short* wt_attn = xb + per;
    short* wt_proj = wt_attn + (size_t)C3 * CC;
    short* qb      = wt_proj + (size_t)CC * CC;
    short* kb      = qb + per;
    short* vt      = kb + per;                     // [B,H,hd,T]
    short* ab      = vt + per;                     // [B,T,C] bf16

    cast_x<<<dim3(MM * CC / (256 * 8)), 256, 0, stream>>>(x, xb);
    tcast<<<dim3(C3 / 64, CC / 64), 256, 0, stream>>>(w_attn, wt_attn, CC, C3);
    tcast<<<dim3(CC / 64, CC / 64), 256, 0, stream>>>(w_proj, wt_proj, CC, CC);

    gemm128<true><<<dim3(C3 / 128, MM / 128), 256, 0, stream>>>(
        xb, wt_attn, b_attn, qb, kb, vt, nullptr, C3, CC);

    flash_attn<<<dim3(8, BB * HH), 512, 0, stream>>>(qb, kb, vt, ab);

    gemm128<false><<<dim3(CC / 128, MM / 128), 256, 0, stream>>>(
        ab, wt_proj, b_proj, nullptr, nullptr, nullptr, out, CC, CC);
}

// Round 10
// 161.394 us; speedup vs baseline: 1.0338x; 1.0338x over previous
//
#include <hip/hip_runtime.h>
#include <hip/hip_bf16.h>
#include <math.h>

// Problem constants
#define BB 4
#define TT 2048
#define CC 1024
#define HH 16
#define HD 64
#define C3 3072
#define MM (BB * TT)   // 8192

typedef __attribute__((ext_vector_type(8))) short bf16x8;  // MFMA A/B frag (4 VGPRs)
typedef __attribute__((ext_vector_type(4))) float f32x4;   // MFMA C/D frag
typedef __attribute__((ext_vector_type(4))) short s16x4;

__device__ inline short f32_to_bf16_bits(float f) {
    unsigned u = __float_as_uint(f);
    u += 0x7fffu + ((u >> 16) & 1u);   // round-to-nearest-even
    return (short)(u >> 16);
}

__device__ inline void async_copy16(const void* g, void* l) {
    __builtin_amdgcn_global_load_lds((const __attribute__((address_space(1))) void*)g,
                                     (__attribute__((address_space(3))) void*)l, 16, 0, 0);
}

// ---------------- fused prep: cast_x (blocks 0..4095) + tcast w_attn (4096..4863)
// + tcast w_proj (4864..5119). Whole-block branching, identical math/addresses to
// the three former kernels — saves 2 launch gaps + 2 dispatch tails.
__global__ __launch_bounds__(256) void prep(const float* __restrict__ x,
                                            const float* __restrict__ w_attn,
                                            const float* __restrict__ w_proj,
                                            short* __restrict__ xb,
                                            short* __restrict__ wt_attn,
                                            short* __restrict__ wt_proj) {
    __shared__ short tile[64][68];
    const int b = blockIdx.x;
    const int tid = threadIdx.x;

    if (b < 4096) {
        // cast x: fp32 -> bf16, flat, 8 elems/thread
        int i = (b * 256 + tid) * 8;
        float4 a = *(const float4*)(x + i);
        float4 c = *(const float4*)(x + i + 4);
        bf16x8 o;
        o[0] = f32_to_bf16_bits(a.x); o[1] = f32_to_bf16_bits(a.y);
        o[2] = f32_to_bf16_bits(a.z); o[3] = f32_to_bf16_bits(a.w);
        o[4] = f32_to_bf16_bits(c.x); o[5] = f32_to_bf16_bits(c.y);
        o[6] = f32_to_bf16_bits(c.z); o[7] = f32_to_bf16_bits(c.w);
        *(bf16x8*)(xb + i) = o;
        return;
    }

    // transpose-cast: w[K][N] fp32 -> wt[N][K] bf16, 64x64 tiles
    const float* w;
    short* wt;
    int K, N, n0, k0;
    if (b < 4096 + 768) {
        int rel = b - 4096;
        w = w_attn; wt = wt_attn; K = CC; N = C3;
        n0 = (rel % 48) * 64; k0 = (rel / 48) * 64;
    } else {
        int rel = b - 4864;
        w = w_proj; wt = wt_proj; K = CC; N = CC;
        n0 = (rel % 16) * 64; k0 = (rel / 16) * 64;
    }
#pragma unroll
    for (int it = 0; it < 4; ++it) {
        int idx = it * 1024 + tid * 4;
        int r = idx >> 6, c = idx & 63;
        float4 v = *(const float4*)&w[(size_t)(k0 + r) * N + n0 + c];
        tile[r][c + 0] = f32_to_bf16_bits(v.x);
        tile[r][c + 1] = f32_to_bf16_bits(v.y);
        tile[r][c + 2] = f32_to_bf16_bits(v.z);
        tile[r][c + 3] = f32_to_bf16_bits(v.w);
    }
    __syncthreads();
#pragma unroll
    for (int it = 0; it < 4; ++it) {
        int idx = it * 256 + tid;
        int rr = idx >> 4, kc = (idx & 15) * 4;
        s16x4 o = { tile[kc + 0][rr], tile[kc + 1][rr], tile[kc + 2][rr], tile[kc + 3][rr] };
        *(s16x4*)&wt[(size_t)(n0 + rr) * K + k0 + kc] = o;
    }
}

// ---------------- bf16 MFMA GEMM v2.2 (r8): 128x128 tile, BK=64, xor-swizzled LDS,
// n-column-grouped XCD swizzle.
template <bool QKV>
__global__ __launch_bounds__(256) void gemm128(const short* __restrict__ A,
                                               const short* __restrict__ Bt,
                                               const float* __restrict__ bias,
                                               short* __restrict__ qb,
                                               short* __restrict__ kb,
                                               short* __restrict__ vt,
                                               float* __restrict__ out,
                                               int N, int Kdim) {
    __shared__ __align__(16) short As[128 * 64];
    __shared__ __align__(16) short Bs[128 * 64];
    const int tid = threadIdx.x;
    const int wave = tid >> 6, lane = tid & 63;
    const int quad = lane >> 4, l16 = lane & 15;
    const int wm = wave >> 1, wn = wave & 1;

    const int nbx = gridDim.x;
    const int cpc = nbx >> 3;                       // columns per class
    const int id = blockIdx.y * nbx + blockIdx.x;
    const int cls = id & 7;
    const int rr = id >> 3;
    const int n_idx = cls * cpc + rr % cpc;
    const int m_idx = rr / cpc;
    const int m0 = m_idx * 128, n0 = n_idx * 128;

    f32x4 acc[4][4] = {};

    for (int k0 = 0; k0 < Kdim; k0 += 64) {
#pragma unroll
        for (int c2 = 0; c2 < 4; ++c2) {
            int g = (wave * 4 + c2) * 64 + lane;      // 0..1023 staging unit
            int row = g >> 3;
            int seg = (g & 7) ^ (row & 7);            // xor swizzle
            async_copy16(A + (size_t)(m0 + row) * Kdim + k0 + seg * 8, As + g * 8);
            async_copy16(Bt + (size_t)(n0 + row) * Kdim + k0 + seg * 8, Bs + g * 8);
        }
        __syncthreads();
#pragma unroll
        for (int ks = 0; ks < 2; ++ks) {
            bf16x8 af[4], bfv[4];
#pragma unroll
            for (int i = 0; i < 4; ++i) {
                int row = wm * 64 + i * 16 + l16;
                int u = (ks * 4 + quad) ^ (row & 7);
                af[i] = *(const bf16x8*)&As[row * 64 + u * 8];
            }
#pragma unroll
            for (int j = 0; j < 4; ++j) {
                int row = wn * 64 + j * 16 + l16;
                int u = (ks * 4 + quad) ^ (row & 7);
                bfv[j] = *(const bf16x8*)&Bs[row * 64 + u * 8];
            }
#pragma unroll
            for (int i = 0; i < 4; ++i)
#pragma unroll
                for (int j = 0; j < 4; ++j)
                    acc[i][j] = __builtin_amdgcn_mfma_f32_16x16x32_bf16(af[i], bfv[j], acc[i][j], 0, 0, 0);
        }
        __syncthreads();
    }

#pragma unroll
    for (int i = 0; i < 4; ++i)
#pragma unroll
        for (int j = 0; j < 4; ++j) {
            int n = n0 + wn * 64 + j * 16 + l16;
            float bv = bias[n];
            if (QKV) {
                int which = n >> 10, cc = n & 1023;
                int h = cc >> 6, d = cc & 63;
                if (which == 2) {
                    // v^T: lane's 4 r-values are 4 consecutive t at fixed d -> one 8B store
                    int m_base = m0 + wm * 64 + i * 16 + quad * 4;
                    int bb = m_base >> 11, t0 = m_base & 2047;
                    unsigned p0 = ((unsigned)(unsigned short)f32_to_bf16_bits(acc[i][j][0] + bv)) |
                                  ((unsigned)(unsigned short)f32_to_bf16_bits(acc[i][j][1] + bv) << 16);
                    unsigned p1 = ((unsigned)(unsigned short)f32_to_bf16_bits(acc[i][j][2] + bv)) |
                                  ((unsigned)(unsigned short)f32_to_bf16_bits(acc[i][j][3] + bv) << 16);
                    uint2 pk = {p0, p1};
                    *(uint2*)(vt + (((size_t)bb * HH + h) * HD + d) * TT + t0) = pk;
                } else {
                    // q-scale folds 1/sqrt(hd)=0.125 AND log2(e) so flash uses raw v_exp_f32 (exp2)
#pragma unroll
                    for (int r = 0; r < 4; ++r) {
                        int m = m0 + wm * 64 + i * 16 + quad * 4 + r;
                        int bb = m >> 11, t = m & 2047;
                        short val = f32_to_bf16_bits((acc[i][j][r] + bv) *
                                                     (which == 0 ? 0.18033688011112042f : 1.0f));
                        size_t off = (((size_t)bb * HH + h) * TT + t) * HD + d;
                        if (which == 0) qb[off] = val;
                        else kb[off] = val;
                    }
                }
            } else {
#pragma unroll
                for (int r = 0; r < 4; ++r) {
                    int m = m0 + wm * 64 + i * 16 + quad * 4 + r;
                    out[(size_t)m * N + n] = acc[i][j][r] + bv;
                }
            }
        }
}

// ---------------- Flash attention v6 (r8-proven, best measured): counted-vmcnt 2-deep
// dbuf, f32 P-tile + cvt_pk on read, exp2 with pre-folded scale, setprio, XCD-locality
// bh-grouping swizzle.
__global__ __launch_bounds__(512, 4) void flash_attn(const short* __restrict__ qb,
                                                     const short* __restrict__ kb,
                                                     const short* __restrict__ vt,
                                                     short* __restrict__ ab) {
    __shared__ __align__(16) short Ksh[2][4096];
    __shared__ __align__(16) short Vsh[2][4096];
    __shared__ __align__(16) float plds[8][16][68];   // P as f32; convert on read

    const int tid = threadIdx.x;
    const int wave = tid >> 6;
    const int lane = tid & 63;
    const int quad = lane >> 4;
    const int l16 = lane & 15;

    // XCD-locality swizzle: bijection [0,512) -> (bh, i) with bh-group constant per n&7
    const int n_hw = blockIdx.y * 8 + blockIdx.x;
    const int lgc = (n_hw & 7) * 64 + (n_hw >> 3);
    const int bh = lgc >> 3;
    const int i = lgc & 7;

    const int njt = 32 - 2 * i;
    const int q_lo = i * 128 + wave * 16;
    const int q_hi = (15 - i) * 128 + wave * 16;

    const short* qball = qb + (size_t)bh * TT * HD;
    const short* kball = kb + (size_t)bh * TT * HD;
    const short* vtall = vt + (size_t)bh * HD * TT;

    const int sidx = wave * 64 + lane;
    const int srow = sidx >> 3;
    const int sseg = (sidx & 7) ^ (srow & 7);
    const short* kgsrc = kball + (size_t)srow * HD + sseg * 8;
    const short* vgsrc = vtall + (size_t)srow * TT + sseg * 8;

    bf16x8 qfh[2], qfl[2];
#pragma unroll
    for (int h = 0; h < 2; ++h) {
        qfh[h] = *(const bf16x8*)(qball + (size_t)(q_hi + l16) * HD + h * 32 + quad * 8);
        qfl[h] = *(const bf16x8*)(qball + (size_t)(q_lo + l16) * HD + h * 32 + quad * 8);
    }

    f32x4 o_hi[4] = {}, o_lo[4] = {};
    float ls_hi[4] = {0.f, 0.f, 0.f, 0.f}, ls_lo[4] = {0.f, 0.f, 0.f, 0.f};

    async_copy16(kgsrc, &Ksh[0][wave * 512]);
    async_copy16(vgsrc, &Vsh[0][wave * 512]);

    for (int jt = 0; jt < njt; ++jt) {
        const int buf = jt & 1;
        if (jt + 1 < njt) {
            async_copy16(kgsrc + (size_t)(jt + 1) * 64 * HD, &Ksh[buf ^ 1][wave * 512]);
            async_copy16(vgsrc + (jt + 1) * 64, &Vsh[buf ^ 1][wave * 512]);
            asm volatile("s_waitcnt vmcnt(2)" : : : "memory");
        } else {
            asm volatile("s_waitcnt vmcnt(0)" : : : "memory");
        }
        __builtin_amdgcn_sched_barrier(0);
        __builtin_amdgcn_s_barrier();
        __builtin_amdgcn_sched_barrier(0);

        const int j0 = jt * 64;

        if (j0 <= q_hi + 15) {
            f32x4 s[4];
            __builtin_amdgcn_s_setprio(1);
#pragma unroll
            for (int cb = 0; cb < 4; ++cb) {
                int row = cb * 16 + l16;
                bf16x8 k0 = *(const bf16x8*)&Ksh[buf][(row * 8 + (quad ^ (row & 7))) * 8];
                bf16x8 k1 = *(const bf16x8*)&Ksh[buf][(row * 8 + ((4 + quad) ^ (row & 7))) * 8];
                f32x4 a = {};
                a = __builtin_amdgcn_mfma_f32_16x16x32_bf16(qfh[0], k0, a, 0, 0, 0);
                a = __builtin_amdgcn_mfma_f32_16x16x32_bf16(qfh[1], k1, a, 0, 0, 0);
                s[cb] = a;
            }
            __builtin_amdgcn_s_setprio(0);
            if (j0 + 64 > q_hi) {
#pragma unroll
                for (int cb = 0; cb < 4; ++cb) {
                    int j = j0 + cb * 16 + l16;
#pragma unroll
                    for (int r = 0; r < 4; ++r)
                        if (j > q_hi + quad * 4 + r) s[cb][r] = -1e30f;
                }
            }
#pragma unroll
            for (int cb = 0; cb < 4; ++cb)
#pragma unroll
                for (int r = 0; r < 4; ++r) {
                    float p;
                    asm("v_exp_f32 %0, %1" : "=v"(p) : "v"(s[cb][r]));
                    ls_hi[r] += p;
                    plds[wave][quad * 4 + r][cb * 16 + l16] = p;
                }
            {
                const float* prow = &plds[wave][l16][0];
                f32x4 pr0 = *(const f32x4*)(prow + quad * 8);
                f32x4 pr1 = *(const f32x4*)(prow + quad * 8 + 4);
                f32x4 pr2 = *(const f32x4*)(prow + 32 + quad * 8);
                f32x4 pr3 = *(const f32x4*)(prow + 32 + quad * 8 + 4);
                union { unsigned u[4]; bf16x8 v; } pa0u, pa1u;
                asm("v_cvt_pk_bf16_f32 %0, %1, %2" : "=v"(pa0u.u[0]) : "v"(pr0[0]), "v"(pr0[1]));
                asm("v_cvt_pk_bf16_f32 %0, %1, %2" : "=v"(pa0u.u[1]) : "v"(pr0[2]), "v"(pr0[3]));
                asm("v_cvt_pk_bf16_f32 %0, %1, %2" : "=v"(pa0u.u[2]) : "v"(pr1[0]), "v"(pr1[1]));
                asm("v_cvt_pk_bf16_f32 %0, %1, %2" : "=v"(pa0u.u[3]) : "v"(pr1[2]), "v"(pr1[3]));
                asm("v_cvt_pk_bf16_f32 %0, %1, %2" : "=v"(pa1u.u[0]) : "v"(pr2[0]), "v"(pr2[1]));
                asm("v_cvt_pk_bf16_f32 %0, %1, %2" : "=v"(pa1u.u[1]) : "v"(pr2[2]), "v"(pr2[3]));
                asm("v_cvt_pk_bf16_f32 %0, %1, %2" : "=v"(pa1u.u[2]) : "v"(pr3[0]), "v"(pr3[1]));
                asm("v_cvt_pk_bf16_f32 %0, %1, %2" : "=v"(pa1u.u[3]) : "v"(pr3[2]), "v"(pr3[3]));
                bf16x8 pa0 = pa0u.v, pa1 = pa1u.v;
                __builtin_amdgcn_s_setprio(1);
#pragma unroll
                for (int db = 0; db < 4; ++db) {
                    int row = db * 16 + l16;
                    bf16x8 v0 = *(const bf16x8*)&Vsh[buf][(row * 8 + (quad ^ (row & 7))) * 8];
                    bf16x8 v1 = *(const bf16x8*)&Vsh[buf][(row * 8 + ((4 + quad) ^ (row & 7))) * 8];
                    o_hi[db] = __builtin_amdgcn_mfma_f32_16x16x32_bf16(pa0, v0, o_hi[db], 0, 0, 0);
                    o_hi[db] = __builtin_amdgcn_mfma_f32_16x16x32_bf16(pa1, v1, o_hi[db], 0, 0, 0);
                }
                __builtin_amdgcn_s_setprio(0);
            }
        }

        if (j0 <= q_lo + 15) {
            f32x4 s[4];
            __builtin_amdgcn_s_setprio(1);
#pragma unroll
            for (int cb = 0; cb < 4; ++cb) {
                int row = cb * 16 + l16;
                bf16x8 k0 = *(const bf16x8*)&Ksh[buf][(row * 8 + (quad ^ (row & 7))) * 8];
                bf16x8 k1 = *(const bf16x8*)&Ksh[buf][(row * 8 + ((4 + quad) ^ (row & 7))) * 8];
                f32x4 a = {};
                a = __builtin_amdgcn_mfma_f32_16x16x32_bf16(qfl[0], k0, a, 0, 0, 0);
                a = __builtin_amdgcn_mfma_f32_16x16x32_bf16(qfl[1], k1, a, 0, 0, 0);
                s[cb] = a;
            }
            __builtin_amdgcn_s_setprio(0);
            if (j0 + 64 > q_lo) {
#pragma unroll
                for (int cb = 0; cb < 4; ++cb) {
                    int j = j0 + cb * 16 + l16;
#pragma unroll
                    for (int r = 0; r < 4; ++r)
                        if (j > q_lo + quad * 4 + r) s[cb][r] = -1e30f;
                }
            }
#pragma unroll
            for (int cb = 0; cb < 4; ++cb)
#pragma unroll
                for (int r = 0; r < 4; ++r) {
                    float p;
                    asm("v_exp_f32 %0, %1" : "=v"(p) : "v"(s[cb][r]));
                    ls_lo[r] += p;
                    plds[wave][quad * 4 + r][cb * 16 + l16] = p;
                }
            {
                const float* prow = &plds[wave][l16][0];
                f32x4 pr0 = *(const f32x4*)(prow + quad * 8);
                f32x4 pr1 = *(const f32x4*)(prow + quad * 8 + 4);
                f32x4 pr2 = *(const f32x4*)(prow + 32 + quad * 8);
                f32x4 pr3 = *(const f32x4*)(prow + 32 + quad * 8 + 4);
                union { unsigned u[4]; bf16x8 v; } pa0u, pa1u;
                asm("v_cvt_pk_bf16_f32 %0, %1, %2" : "=v"(pa0u.u[0]) : "v"(pr0[0]), "v"(pr0[1]));
                asm("v_cvt_pk_bf16_f32 %0, %1, %2" : "=v"(pa0u.u[1]) : "v"(pr0[2]), "v"(pr0[3]));
                asm("v_cvt_pk_bf16_f32 %0, %1, %2" : "=v"(pa0u.u[2]) : "v"(pr1[0]), "v"(pr1[1]));
                asm("v_cvt_pk_bf16_f32 %0, %1, %2" : "=v"(pa0u.u[3]) : "v"(pr1[2]), "v"(pr1[3]));
                asm("v_cvt_pk_bf16_f32 %0, %1, %2" : "=v"(pa1u.u[0]) : "v"(pr2[0]), "v"(pr2[1]));
                asm("v_cvt_pk_bf16_f32 %0, %1, %2" : "=v"(pa1u.u[1]) : "v"(pr2[2]), "v"(pr2[3]));
                asm("v_cvt_pk_bf16_f32 %0, %1, %2" : "=v"(pa1u.u[2]) : "v"(pr3[0]), "v"(pr3[1]));
                asm("v_cvt_pk_bf16_f32 %0, %1, %2" : "=v"(pa1u.u[3]) : "v"(pr3[2]), "v"(pr3[3]));
                bf16x8 pa0 = pa0u.v, pa1 = pa1u.v;
                __builtin_amdgcn_s_setprio(1);
#pragma unroll
                for (int db = 0; db < 4; ++db) {
                    int row = db * 16 + l16;
                    bf16x8 v0 = *(const bf16x8*)&Vsh[buf][(row * 8 + (quad ^ (row & 7))) * 8];
                    bf16x8 v1 = *(const bf16x8*)&Vsh[buf][(row * 8 + ((4 + quad) ^ (row & 7))) * 8];
                    o_lo[db] = __builtin_amdgcn_mfma_f32_16x16x32_bf16(pa0, v0, o_lo[db], 0, 0, 0);
                    o_lo[db] = __builtin_amdgcn_mfma_f32_16x16x32_bf16(pa1, v1, o_lo[db], 0, 0, 0);
                }
                __builtin_amdgcn_s_setprio(0);
            }
        }
        __builtin_amdgcn_sched_barrier(0);
        __builtin_amdgcn_s_barrier();
    }

    const int b = bh >> 4, hd0 = (bh & 15) * HD;
    float inv_h[4], inv_l[4];
#pragma unroll
    for (int r = 0; r < 4; ++r) {
        float th = ls_hi[r], tl = ls_lo[r];
#pragma unroll
        for (int off = 1; off < 16; off <<= 1) {
            th += __shfl_xor(th, off, 64);
            tl += __shfl_xor(tl, off, 64);
        }
        inv_h[r] = 1.0f / th;
        inv_l[r] = 1.0f / tl;
    }
#pragma unroll
    for (int r = 0; r < 4; ++r) {
        int qh = q_hi + quad * 4 + r;
        int ql = q_lo + quad * 4 + r;
#pragma unroll
        for (int db = 0; db < 4; ++db) {
            ab[((size_t)(b * TT + qh)) * CC + hd0 + db * 16 + l16] =
                f32_to_bf16_bits(o_hi[db][r] * inv_h[r]);
            ab[((size_t)(b * TT + ql)) * CC + hd0 + db * 16 + l16] =
                f32_to_bf16_bits(o_lo[db][r] * inv_l[r]);
        }
    }
}

extern "C" void kernel_launch(void* const* d_in, const int* in_sizes, int n_in,
                              void* d_out, int out_size, void* d_ws, size_t ws_size,
                              hipStream_t stream) {
    const float* x      = (const float*)d_in[0];
    const float* w_attn = (const float*)d_in[1];
    const float* b_attn = (const float*)d_in[2];
    const float* w_proj = (const float*)d_in[3];
    const float* b_proj = (const float*)d_in[4];
    float* out = (float*)d_out;

    const size_t per = (size_t)BB * HH * TT * HD;  // 8,388,608
    short* xb      = (short*)d_ws;
    short* wt_attn = xb + per;
    short* wt_proj = wt_attn + (size_t)C3 * CC;
    short* qb      = wt_proj + (size_t)CC * CC;
    short* kb      = qb + per;
    short* vt      = kb + per;                     // [B,H,hd,T]
    short* ab      = vt + per;                     // [B,T,C] bf16

    prep<<<dim3(4096 + 768 + 256), 256, 0, stream>>>(x, w_attn, w_proj,
                                                     xb, wt_attn, wt_proj);

    gemm128<true><<<dim3(C3 / 128, MM / 128), 256, 0, stream>>>(
        xb, wt_attn, b_attn, qb, kb, vt, nullptr, C3, CC);

    flash_attn<<<dim3(8, BB * HH), 512, 0, stream>>>(qb, kb, vt, ab);

    gemm128<false><<<dim3(CC / 128, MM / 128), 256, 0, stream>>>(
        ab, wt_proj, b_proj, nullptr, nullptr, nullptr, out, CC, CC);
}